// Round 13
// baseline (659.813 us; speedup 1.0000x reference)
//
#include <hip/hip_runtime.h>
#include <cstddef>
#include <cstdint>

#define B_    2
#define S_    2048
#define DIN_  1024
#define H_    16
#define DK_   1024
#define DV_   1024
#define DH_   64
#define DOUT_ 1024
#define M_    (B_ * S_)

typedef __attribute__((ext_vector_type(8)))  short short8;
typedef __attribute__((ext_vector_type(4)))  float float4v;
typedef __attribute__((ext_vector_type(16))) float float16v;
typedef _Float16 half8v __attribute__((ext_vector_type(8)));

__device__ __forceinline__ float bf16s_to_f(short s) {
  union { unsigned int u; float f; } cv;
  cv.u = ((unsigned int)(unsigned short)s) << 16;
  return cv.f;
}
__device__ __forceinline__ short f_to_bf16s(float f) {
  union { float f; unsigned int u; } cv;
  cv.f = f;
  unsigned int u = cv.u + 0x7FFFu + ((cv.u >> 16) & 1u);
  return (short)(u >> 16);
}
__device__ __forceinline__ short f_to_f16s(float f) {
  union { _Float16 h; short s; } cv;
  cv.h = (_Float16)f;
  return cv.s;
}
// packed f32x2 -> f16x2 (v_cvt_pkrtz_f16_f32), returned as a raw 32-bit word
__device__ __forceinline__ unsigned pkrtz_u32(float a, float b) {
  union { __fp16 __attribute__((ext_vector_type(2))) h2; unsigned u; } cv;
  cv.h2 = __builtin_amdgcn_cvt_pkrtz(a, b);   // [0]=a, [1]=b
  return cv.u;
}
__device__ __forceinline__ void gll16(const void* g, void* l) {
  __builtin_amdgcn_global_load_lds(
      (const __attribute__((address_space(1))) unsigned int*)g,
      (__attribute__((address_space(3))) unsigned int*)l, 16, 0, 0);
}

// ---------------- cast f32 -> bf16 (4 elems/thread) ----------------
__global__ __launch_bounds__(256) void cast_kernel(const float* __restrict__ in,
                                                   short* __restrict__ out, int n4) {
  int i = blockIdx.x * 256 + threadIdx.x;
  if (i >= n4) return;
  float4 v = ((const float4*)in)[i];
  union { ushort4 u; short s[4]; } o;
  o.s[0] = f_to_bf16s(v.x); o.s[1] = f_to_bf16s(v.y);
  o.s[2] = f_to_bf16s(v.z); o.s[3] = f_to_bf16s(v.w);
  ((ushort4*)out)[i] = o.u;
}

// ---------------- content bias: CBs[b,h,s] = SC*dot(x[b,s,:],Wcb[h,:]) ----
__global__ __launch_bounds__(256) void cb_kernel(const float* __restrict__ x,
                                                 const float* __restrict__ Wcb,
                                                 float* __restrict__ CBs) {
  __shared__ float xs[DIN_];
  const int row = blockIdx.x;  // b*S + s
  const int tid = threadIdx.x;
  #pragma unroll
  for (int it = 0; it < 4; ++it)
    xs[tid + it * 256] = x[(size_t)row * DIN_ + tid + it * 256];
  __syncthreads();
  const int lane = tid & 63, w = tid >> 6;
  const float SC = 0.125f * 1.44269504088896f;
  #pragma unroll
  for (int hh = 0; hh < 4; ++hh) {
    const int hidx = w * 4 + hh;
    float p = 0.f;
    for (int c = lane; c < DIN_; c += 64)
      p += xs[c] * Wcb[(size_t)hidx * DIN_ + c];
    #pragma unroll
    for (int mk = 1; mk < 64; mk <<= 1) p += __shfl_xor(p, mk);
    if (lane == 0) {
      const int bb = row / S_, ss = row % S_;
      CBs[((size_t)bb * H_ + hidx) * S_ + ss] = p * SC;
    }
  }
}

// ---------------- bf16 NT GEMM: C[M,ND] = A[M,1024] * Bw[ND,1024]^T ----
// global_load_lds width=16 staging, both-sides XOR swizzle, single-buffer
// 2-barrier k-loop, 32 KB LDS -> 4 blocks/CU. (R8-measured, keep.)
// modes: 2 f32+bias+resid; 4 f16; 5 f16 transposed ([b][col][s]) + bias;
// 6 f16 dual-output (col<1024 -> outb, col>=1024 -> outb + M*1024) for the
// fused Q||K projection (Wqb/Wkb and Qf/Kf are workspace-contiguous).
__global__ __launch_bounds__(256, 4) void gemm_nt(
    const short* __restrict__ A, const short* __restrict__ Bw,
    const float* __restrict__ bias, const float* __restrict__ resid,
    short* __restrict__ outb, float* __restrict__ outf, int mode) {
  const int KD = 1024, ND = 1024;
  __shared__ __align__(16) short As[64 * 128];   // 16 KB, swizzled
  __shared__ __align__(16) short Bs[64 * 128];   // 16 KB, swizzled
  const int tid  = threadIdx.x;
  const int lane = tid & 63;
  const int w    = tid >> 6;
  const int quad = lane >> 4;
  const int l16  = lane & 15;
  const int m0   = blockIdx.y * 64;
  const int n0   = blockIdx.x * 64;
  const int wm   = (w >> 1) * 32;
  const int wn   = (w & 1) * 32;

  const int drow = lane >> 4;
  const int dp   = lane & 15;

  const float4v zero = {0.f, 0.f, 0.f, 0.f};
  float4v acc[2][2];
  acc[0][0] = zero; acc[0][1] = zero; acc[1][0] = zero; acc[1][1] = zero;

  for (int k0 = 0; k0 < KD; k0 += 128) {
    __syncthreads();   // previous k-step's As/Bs consumers done
    #pragma unroll
    for (int cc = 0; cc < 4; ++cc) {
      const int n = w * 4 + cc;
      const int r = 4 * n + drow;
      const int l = dp ^ (r & 15);
      gll16(A  + (size_t)(m0 + r) * KD + k0 + l * 8, &As[n * 512]);
      gll16(Bw + (size_t)(n0 + r) * KD + k0 + l * 8, &Bs[n * 512]);
    }
    __syncthreads();   // drain (compiler emits vmcnt(0) before s_barrier)
    #pragma unroll
    for (int ks = 0; ks < 4; ++ks) {
      const int ca = ((ks * 4 + quad) ^ l16) * 8;   // swizzled chunk offset
      short8 af0 = *(short8*)&As[(wm + l16) * 128 + ca];
      short8 af1 = *(short8*)&As[(wm + 16 + l16) * 128 + ca];
      short8 bg0 = *(short8*)&Bs[(wn + l16) * 128 + ca];
      short8 bg1 = *(short8*)&Bs[(wn + 16 + l16) * 128 + ca];
      acc[0][0] = __builtin_amdgcn_mfma_f32_16x16x32_bf16(af0, bg0, acc[0][0], 0, 0, 0);
      acc[0][1] = __builtin_amdgcn_mfma_f32_16x16x32_bf16(af0, bg1, acc[0][1], 0, 0, 0);
      acc[1][0] = __builtin_amdgcn_mfma_f32_16x16x32_bf16(af1, bg0, acc[1][0], 0, 0, 0);
      acc[1][1] = __builtin_amdgcn_mfma_f32_16x16x32_bf16(af1, bg1, acc[1][1], 0, 0, 0);
    }
  }

  #pragma unroll
  for (int mt = 0; mt < 2; ++mt)
    #pragma unroll
    for (int nt = 0; nt < 2; ++nt)
      #pragma unroll
      for (int r = 0; r < 4; ++r) {
        int row = m0 + wm + mt * 16 + quad * 4 + r;   // verified C/D layout
        int col = n0 + wn + nt * 16 + l16;
        float v = acc[mt][nt][r];
        if (mode == 1 || mode == 5) v += bias[col];
        if (mode == 2)
          outf[(size_t)row * ND + col] = v + bias[col] + resid[(size_t)row * ND + col];
        else if (mode == 5) {
          int bb = row >> 11, ss = row & 2047;
          outb[((size_t)bb * DV_ + col) * S_ + ss] = f_to_f16s(v);
        } else if (mode == 6) {
          short* dst = outb + ((col >> 10) ? (size_t)M_ * 1024 : 0) +
                       (size_t)row * 1024 + (col & 1023);
          *dst = f_to_f16s(v);
        } else if (mode == 4)
          outb[(size_t)row * ND + col] = f_to_f16s(v);
        else
          outb[(size_t)row * ND + col] = f_to_bf16s(v);
      }
}

// ---------------- fused collaborative attention v8 (flat pipeline) --------
// R11's counted-vmcnt structure, with the j-tile loop FLATTENED into one
// 256-step pipeline that never restarts: the 3-buffer K rotation continues
// across tile boundaries (chunk s+2 issued at step s); q-prefetch crosses
// the boundary (k wraps to 0); Vt for tile jt is reg-loaded at t==0 and
// ds_written at t==4 (PV reads it at t==15; previous tile's PV finished
// before t==0, so single-buffer Vt is race-free), with lgkmcnt(0) folded
// into step-4's barrier; cb is read direct from L2-hot global at softmax
// (cb_s deleted). Removes 2 full __syncthreads drains + the K-refill
// bubble + the dead prefetch slot per tile. vmcnt accounting is count-
// based (order-free): vmcnt(12) at t==0 (vreg in flight), vmcnt(8)+
// lgkmcnt(0) at t==4, vmcnt(8) elsewhere.
__global__ __launch_bounds__(256, 2) void attn_kernel(
    const short* __restrict__ Qf, const short* __restrict__ Kf,
    const short* __restrict__ Vtf, const float* __restrict__ mixing,
    const float* __restrict__ CBs, short* __restrict__ ctxb) {
  __shared__ __align__(16) short KsF[3 * 128 * 64]; // 3 bufs, swizzled, 48 KB
  __shared__ __align__(16) short Vt[64][136];       // V^T tile [dv][j], f16
  __shared__ __align__(16) short mix_s[DK_];        // f16(mix*SC)

  const int tid  = threadIdx.x;
  const int lane = tid & 63;
  const int l32  = lane & 31;
  const int l1   = lane >> 5;
  const int w    = tid >> 6;

  // XCD-locality remap: xcd class = blk&7; b per xcd-half, 4 heads per xcd
  const int F    = blockIdx.x;
  const int xcd  = F & 7, rest = F >> 3;
  const int b    = xcd >> 2;
  const int h    = (xcd & 3) * 4 + (rest & 3);
  const int i0   = (rest >> 2) * 128;

  const float SC = 0.125f * 1.44269504088896f;
  for (int c = tid; c < DK_; c += 256) {
    union { _Float16 h; short s; } cv;
    cv.h = (_Float16)(mixing[(size_t)h * DK_ + c] * SC);
    mix_s[c] = cv.s;
  }

  const int iq = i0 + w * 32 + l32;
  const short* qptr  = Qf + ((size_t)b * S_ + iq) * DK_;
  const short* kbase = Kf + (size_t)b * S_ * DK_;
  const short* vtb   = Vtf + ((size_t)b * DV_ + h * DH_) * S_;
  const float* cbp   = CBs + ((size_t)b * H_ + h) * S_;

  float16v accS[4], accO[2];
  #pragma unroll
  for (int f = 0; f < 4; ++f)
    #pragma unroll
    for (int r = 0; r < 16; ++r) accS[f][r] = 0.f;
  #pragma unroll
  for (int g = 0; g < 2; ++g)
    #pragma unroll
    for (int r = 0; r < 16; ++r) accO[g][r] = 0.f;
  float m_run = -1e30f, l_run = 0.f;

  // K DMA geometry (64-col chunks): call n covers rows 8n..8n+7;
  // lane: row r = 8n + (lane>>3), phys 16B-chunk p = lane&7 holds
  // logical chunk l = p ^ (r&7)
  const int nrow = lane >> 3;
  const int dp8  = lane & 7;

  const int vrow = tid >> 2;             // Vt stage: 64 rows, 4 thr/row
  const int vseg = (tid & 3) * 32;

  // ---- prologue: issue chunk 0 (buf0) + chunk 1 (buf1), load q(0) ----
  #pragma unroll
  for (int cc = 0; cc < 4; ++cc) {
    const int n = w * 4 + cc;
    const int r = 8 * n + nrow;
    const int lchunk = dp8 ^ (r & 7);
    gll16(kbase + (size_t)r * DK_ + lchunk * 8, &KsF[n * 512]);
  }
  #pragma unroll
  for (int cc = 0; cc < 4; ++cc) {
    const int n = w * 4 + cc;
    const int r = 8 * n + nrow;
    const int lchunk = dp8 ^ (r & 7);
    gll16(kbase + (size_t)r * DK_ + 64 + lchunk * 8, &KsF[8192 + n * 512]);
  }
  half8v qcur[4], qnext[4];
  #pragma unroll
  for (int ks = 0; ks < 4; ++ks) {
    qcur[ks] = *(const half8v*)(qptr + ks * 16 + l1 * 8);
    qnext[ks] = qcur[ks];
  }
  // chunk0 drained (chunk1 + q0 may fly); mix_s writes visible
  __builtin_amdgcn_sched_barrier(0);
  asm volatile("s_waitcnt vmcnt(8) lgkmcnt(0)" ::: "memory");
  __builtin_amdgcn_s_barrier();
  __builtin_amdgcn_sched_barrier(0);

  int rd = 0;           // buffer holding chunk s
  short8 vreg[4];       // Vt staging registers

  for (int s = 0; s < 256; ++s) {
    const int jt = s >> 4, t = s & 15;

    // ---- (1) issue chunk s+2 into buf (rd+2)%3 ----
    if (s < 254) {
      const int s2 = s + 2;
      const int jt2 = s2 >> 4, t2 = s2 & 15;
      int wr = rd + 2; if (wr >= 3) wr -= 3;
      #pragma unroll
      for (int cc = 0; cc < 4; ++cc) {
        const int n = w * 4 + cc;
        const int r = 8 * n + nrow;
        const int lchunk = dp8 ^ (r & 7);
        gll16(kbase + (size_t)(jt2 * 128 + r) * DK_ + t2 * 64 + lchunk * 8,
              &KsF[wr * 8192 + n * 512]);
      }
    }
    // ---- (2) q prefetch for step s+1 (k wraps across tile boundary) ----
    if (s < 255) {
      const int t1 = (s + 1) & 15;
      #pragma unroll
      for (int ks = 0; ks < 4; ++ks)
        qnext[ks] = *(const half8v*)(qptr + t1 * 64 + ks * 16 + l1 * 8);
    }
    // ---- (3) Vt pipeline: load regs at t==0, LDS-write at t==4 ----
    if (t == 0) {
      #pragma unroll
      for (int c = 0; c < 4; ++c)
        vreg[c] = *(const short8*)(vtb + (size_t)vrow * S_ + jt * 128 + vseg + c * 8);
    } else if (t == 4) {
      #pragma unroll
      for (int c = 0; c < 4; ++c)
        *(short8*)&Vt[vrow][vseg + c * 8] = vreg[c];
    }
    // ---- (4) compute chunk s from buf rd ----
    const short* kb = &KsF[rd * 8192];
    __builtin_amdgcn_s_setprio(1);
    #pragma unroll
    for (int ks = 0; ks < 4; ++ks) {
      half8v mf = *(half8v*)&mix_s[t * 64 + ks * 16 + l1 * 8];
      half8v qm = qcur[ks] * mf;                    // v_pk_mul_f16
      const int poff = (((2 * ks + l1) ^ (l32 & 7)) * 8) + l32 * 64;
      #pragma unroll
      for (int f = 0; f < 4; ++f) {
        half8v af = *(half8v*)&kb[f * 2048 + poff];
        accS[f] = __builtin_amdgcn_mfma_f32_32x32x16_f16(af, qm, accS[f], 0, 0, 0);
      }
    }
    __builtin_amdgcn_s_setprio(0);
    #pragma unroll
    for (int ks = 0; ks < 4; ++ks) qcur[ks] = qnext[ks];

    // ---- (5) softmax + PV at tile end ----
    if (t == 15) {
      float tmax = -1e30f;
      #pragma unroll
      for (int f = 0; f < 4; ++f)
        #pragma unroll
        for (int q = 0; q < 4; ++q) {
          float4 cbq = *(const float4*)(cbp + jt * 128 + f * 32 + q * 8 + l1 * 4);
          #pragma unroll
          for (int c = 0; c < 4; ++c) {
            accS[f][4 * q + c] += ((const float*)&cbq)[c];
            tmax = fmaxf(tmax, accS[f][4 * q + c]);
          }
        }
      tmax = fmaxf(tmax, __shfl_xor(tmax, 32));
      const float mnew = fmaxf(m_run, tmax);
      const float alpha = exp2f(m_run - mnew);
      float tsum = 0.f;
      #pragma unroll
      for (int f = 0; f < 4; ++f)
        #pragma unroll
        for (int r = 0; r < 16; ++r) {
          float pv = exp2f(accS[f][r] - mnew);
          accS[f][r] = pv;
          tsum += pv;
        }
      tsum += __shfl_xor(tsum, 32);
      l_run = l_run * alpha + tsum;
      m_run = mnew;
      #pragma unroll
      for (int g = 0; g < 2; ++g)
        #pragma unroll
        for (int r = 0; r < 16; ++r) accO[g][r] *= alpha;

      #pragma unroll
      for (int cpv = 0; cpv < 8; ++cpv) {
        const int tt = cpv & 1, fp = cpv >> 1;
        float xo[4], yo[4], lo[4], hi[4];
        #pragma unroll
        for (int c = 0; c < 4; ++c) {
          xo[c] = __shfl_xor(accS[fp][8 * tt + c], 32);
          yo[c] = __shfl_xor(accS[fp][8 * tt + 4 + c], 32);
        }
        #pragma unroll
        for (int c = 0; c < 4; ++c) {
          lo[c] = l1 ? yo[c] : accS[fp][8 * tt + c];
          hi[c] = l1 ? accS[fp][8 * tt + 4 + c] : xo[c];
        }
        union { half8v v; unsigned u[4]; } pb;
        pb.u[0] = pkrtz_u32(lo[0], lo[1]);
        pb.u[1] = pkrtz_u32(lo[2], lo[3]);
        pb.u[2] = pkrtz_u32(hi[0], hi[1]);
        pb.u[3] = pkrtz_u32(hi[2], hi[3]);
        #pragma unroll
        for (int g = 0; g < 2; ++g) {
          half8v vf = *(half8v*)&Vt[g * 32 + l32][cpv * 16 + l1 * 8];
          accO[g] = __builtin_amdgcn_mfma_f32_32x32x16_f16(vf, pb.v, accO[g], 0, 0, 0);
        }
      }
      // reset accS for the next tile
      #pragma unroll
      for (int f = 0; f < 4; ++f)
        #pragma unroll
        for (int r = 0; r < 16; ++r) accS[f][r] = 0.f;
    }

    // ---- (6) end-of-step: counted wait + raw barrier ----
    if (s < 255) {
      __builtin_amdgcn_sched_barrier(0);
      if (t == 0)      asm volatile("s_waitcnt vmcnt(12)" ::: "memory");
      else if (t == 4) asm volatile("s_waitcnt vmcnt(8) lgkmcnt(0)" ::: "memory");
      else             asm volatile("s_waitcnt vmcnt(8)" ::: "memory");
      __builtin_amdgcn_s_barrier();
      __builtin_amdgcn_sched_barrier(0);
    }
    rd = (rd + 1 == 3) ? 0 : rd + 1;
  }

  // ---- epilogue: normalize, store ctx (bf16) ----
  const float rl = 1.0f / l_run;
  short* cbase = ctxb + ((size_t)b * S_ + iq) * DV_ + h * DH_;
  #pragma unroll
  for (int g = 0; g < 2; ++g)
    #pragma unroll
    for (int q = 0; q < 4; ++q) {
      const int dv = g * 32 + 8 * q + 4 * l1;
      union { ushort4 u4; short s[4]; } ov;
      #pragma unroll
      for (int r = 0; r < 4; ++r)
        ov.s[r] = f_to_bf16s(accO[g][4 * q + r] * rl);
      *(ushort4*)(cbase + dv) = ov.u4;
    }
}

// ---------------- LayerNorm in-place on d_out ----------------
__global__ __launch_bounds__(256) void ln_kernel(float* __restrict__ out,
                                                 const float* __restrict__ gamma,
                                                 const float* __restrict__ beta) {
  __shared__ float red[8];
  const int row = blockIdx.x;
  const int tid = threadIdx.x;
  float* p = out + (size_t)row * DOUT_;
  float4 v = ((const float4*)p)[tid];
  float s = v.x + v.y + v.z + v.w;
  #pragma unroll
  for (int mk = 1; mk < 64; mk <<= 1) s += __shfl_xor(s, mk);
  if ((tid & 63) == 0) red[tid >> 6] = s;
  __syncthreads();
  const float mean = (red[0] + red[1] + red[2] + red[3]) * (1.0f / 1024.0f);
  const float d0 = v.x - mean, d1 = v.y - mean, d2 = v.z - mean, d3 = v.w - mean;
  float sq = d0 * d0 + d1 * d1 + d2 * d2 + d3 * d3;
  #pragma unroll
  for (int mk = 1; mk < 64; mk <<= 1) sq += __shfl_xor(sq, mk);
  if ((tid & 63) == 0) red[4 + (tid >> 6)] = sq;
  __syncthreads();
  const float var = (red[4] + red[5] + red[6] + red[7]) * (1.0f / 1024.0f);
  const float rstd = rsqrtf(var + 1e-5f);
  float4 g = ((const float4*)gamma)[tid];
  float4 bt = ((const float4*)beta)[tid];
  float4 o;
  o.x = d0 * rstd * g.x + bt.x;
  o.y = d1 * rstd * g.y + bt.y;
  o.z = d2 * rstd * g.z + bt.z;
  o.w = d3 * rstd * g.w + bt.w;
  ((float4*)p)[tid] = o;
}

extern "C" void kernel_launch(void* const* d_in, const int* in_sizes, int n_in,
                              void* d_out, int out_size, void* d_ws, size_t ws_size,
                              hipStream_t stream) {
  (void)in_sizes; (void)n_in; (void)out_size; (void)ws_size;
  const float* x      = (const float*)d_in[0];
  const float* Wq     = (const float*)d_in[1];
  const float* Wk     = (const float*)d_in[2];
  const float* Wcb    = (const float*)d_in[3];
  const float* Wv     = (const float*)d_in[4];
  const float* bv     = (const float*)d_in[5];
  const float* mixing = (const float*)d_in[6];
  const float* Wd     = (const float*)d_in[7];
  const float* bd     = (const float*)d_in[8];
  const float* gamma  = (const float*)d_in[9];
  const float* beta   = (const float*)d_in[10];
  float* out = (float*)d_out;

  short* p = (short*)d_ws;
  short* xb   = p; p += (size_t)M_ * DIN_;
  short* Qf   = p; p += (size_t)M_ * DK_;      // f16
  short* Kf   = p; p += (size_t)M_ * DK_;      // f16 (contiguous after Qf)
  short* Vtf  = p; p += (size_t)B_ * DV_ * S_; // f16, [b][dv][s]
  short* ctxb = p; p += (size_t)M_ * DV_;      // bf16
  short* Wqb  = p; p += (size_t)DK_ * DIN_;
  short* Wkb  = p; p += (size_t)DK_ * DIN_;    // contiguous after Wqb
  short* Wvb  = p; p += (size_t)DV_ * DIN_;
  short* Wdb  = p; p += (size_t)DOUT_ * DV_;
  float* CBs  = (float*)p;   // B*H*S floats
  (void)Kf; (void)Wkb;

  cast_kernel<<<dim3(M_ * DIN_ / 1024), 256, 0, stream>>>(x, xb, M_ * DIN_ / 4);
  cast_kernel<<<dim3(DK_ * DIN_ / 1024), 256, 0, stream>>>(Wq, Wqb, DK_ * DIN_ / 4);
  cast_kernel<<<dim3(DK_ * DIN_ / 1024), 256, 0, stream>>>(Wk, Wkb, DK_ * DIN_ / 4);
  cast_kernel<<<dim3(DV_ * DIN_ / 1024), 256, 0, stream>>>(Wv, Wvb, DV_ * DIN_ / 4);
  cast_kernel<<<dim3(DOUT_ * DV_ / 1024), 256, 0, stream>>>(Wd, Wdb, DOUT_ * DV_ / 4);
  cb_kernel<<<dim3(M_), 256, 0, stream>>>(x, Wcb, CBs);

  // fused Q||K projection: B = [Wqb;Wkb] (contiguous), out = [Qf;Kf] via mode 6
  dim3 gqk(2048 / 64, M_ / 64);
  gemm_nt<<<gqk, 256, 0, stream>>>(xb, Wqb, nullptr, nullptr, Qf, nullptr, 6);
  dim3 gg(DOUT_ / 64, M_ / 64);
  gemm_nt<<<gg, 256, 0, stream>>>(xb, Wvb, bv, nullptr, Vtf, nullptr, 5);

  attn_kernel<<<dim3(512), 256, 0, stream>>>(Qf, Kf, Vtf, mixing, CBs, ctxb);

  gemm_nt<<<gg, 256, 0, stream>>>(ctxb, Wdb, bd, x, nullptr, out, 2);
  ln_kernel<<<dim3(M_), 256, 0, stream>>>(out, gamma, beta);
}

// Round 14
// 616.251 us; speedup vs baseline: 1.0707x; 1.0707x over previous
//
#include <hip/hip_runtime.h>
#include <cstddef>
#include <cstdint>

#define B_    2
#define S_    2048
#define DIN_  1024
#define H_    16
#define DK_   1024
#define DV_   1024
#define DH_   64
#define DOUT_ 1024
#define M_    (B_ * S_)

typedef __attribute__((ext_vector_type(8)))  short short8;
typedef __attribute__((ext_vector_type(4)))  float float4v;
typedef __attribute__((ext_vector_type(16))) float float16v;
typedef _Float16 half8v __attribute__((ext_vector_type(8)));

__device__ __forceinline__ float bf16s_to_f(short s) {
  union { unsigned int u; float f; } cv;
  cv.u = ((unsigned int)(unsigned short)s) << 16;
  return cv.f;
}
__device__ __forceinline__ short f_to_bf16s(float f) {
  union { float f; unsigned int u; } cv;
  cv.f = f;
  unsigned int u = cv.u + 0x7FFFu + ((cv.u >> 16) & 1u);
  return (short)(u >> 16);
}
__device__ __forceinline__ short f_to_f16s(float f) {
  union { _Float16 h; short s; } cv;
  cv.h = (_Float16)f;
  return cv.s;
}
// packed f32x2 -> f16x2 (v_cvt_pkrtz_f16_f32), returned as a raw 32-bit word
__device__ __forceinline__ unsigned pkrtz_u32(float a, float b) {
  union { __fp16 __attribute__((ext_vector_type(2))) h2; unsigned u; } cv;
  cv.h2 = __builtin_amdgcn_cvt_pkrtz(a, b);   // [0]=a, [1]=b
  return cv.u;
}
__device__ __forceinline__ void gll16(const void* g, void* l) {
  __builtin_amdgcn_global_load_lds(
      (const __attribute__((address_space(1))) unsigned int*)g,
      (__attribute__((address_space(3))) unsigned int*)l, 16, 0, 0);
}

// ---------------- cast f32 -> bf16 (4 elems/thread) ----------------
__global__ __launch_bounds__(256) void cast_kernel(const float* __restrict__ in,
                                                   short* __restrict__ out, int n4) {
  int i = blockIdx.x * 256 + threadIdx.x;
  if (i >= n4) return;
  float4 v = ((const float4*)in)[i];
  union { ushort4 u; short s[4]; } o;
  o.s[0] = f_to_bf16s(v.x); o.s[1] = f_to_bf16s(v.y);
  o.s[2] = f_to_bf16s(v.z); o.s[3] = f_to_bf16s(v.w);
  ((ushort4*)out)[i] = o.u;
}

// ---------------- content bias: CBs[b,h,s] = SC*dot(x[b,s,:],Wcb[h,:]) ----
__global__ __launch_bounds__(256) void cb_kernel(const float* __restrict__ x,
                                                 const float* __restrict__ Wcb,
                                                 float* __restrict__ CBs) {
  __shared__ float xs[DIN_];
  const int row = blockIdx.x;  // b*S + s
  const int tid = threadIdx.x;
  #pragma unroll
  for (int it = 0; it < 4; ++it)
    xs[tid + it * 256] = x[(size_t)row * DIN_ + tid + it * 256];
  __syncthreads();
  const int lane = tid & 63, w = tid >> 6;
  const float SC = 0.125f * 1.44269504088896f;
  #pragma unroll
  for (int hh = 0; hh < 4; ++hh) {
    const int hidx = w * 4 + hh;
    float p = 0.f;
    for (int c = lane; c < DIN_; c += 64)
      p += xs[c] * Wcb[(size_t)hidx * DIN_ + c];
    #pragma unroll
    for (int mk = 1; mk < 64; mk <<= 1) p += __shfl_xor(p, mk);
    if (lane == 0) {
      const int bb = row / S_, ss = row % S_;
      CBs[((size_t)bb * H_ + hidx) * S_ + ss] = p * SC;
    }
  }
}

// ---------------- bf16 NT GEMM: C[M,ND] = A[M,1024] * Bw[ND,1024]^T ----
// global_load_lds width=16 staging, both-sides XOR swizzle, single-buffer
// 2-barrier k-loop, 32 KB LDS -> 4 blocks/CU. (R8-measured, keep.)
// modes: 2 f32+bias+resid; 4 f16; 5 f16 transposed ([b][col][s]) + bias;
// 6 f16 dual-output (col<1024 -> outb, col>=1024 -> outb + M*1024) for the
// fused Q||K projection (Wqb/Wkb and Qf/Kf are workspace-contiguous).
__global__ __launch_bounds__(256, 4) void gemm_nt(
    const short* __restrict__ A, const short* __restrict__ Bw,
    const float* __restrict__ bias, const float* __restrict__ resid,
    short* __restrict__ outb, float* __restrict__ outf, int mode) {
  const int KD = 1024, ND = 1024;
  __shared__ __align__(16) short As[64 * 128];   // 16 KB, swizzled
  __shared__ __align__(16) short Bs[64 * 128];   // 16 KB, swizzled
  const int tid  = threadIdx.x;
  const int lane = tid & 63;
  const int w    = tid >> 6;
  const int quad = lane >> 4;
  const int l16  = lane & 15;
  const int m0   = blockIdx.y * 64;
  const int n0   = blockIdx.x * 64;
  const int wm   = (w >> 1) * 32;
  const int wn   = (w & 1) * 32;

  const int drow = lane >> 4;
  const int dp   = lane & 15;

  const float4v zero = {0.f, 0.f, 0.f, 0.f};
  float4v acc[2][2];
  acc[0][0] = zero; acc[0][1] = zero; acc[1][0] = zero; acc[1][1] = zero;

  for (int k0 = 0; k0 < KD; k0 += 128) {
    __syncthreads();   // previous k-step's As/Bs consumers done
    #pragma unroll
    for (int cc = 0; cc < 4; ++cc) {
      const int n = w * 4 + cc;
      const int r = 4 * n + drow;
      const int l = dp ^ (r & 15);
      gll16(A  + (size_t)(m0 + r) * KD + k0 + l * 8, &As[n * 512]);
      gll16(Bw + (size_t)(n0 + r) * KD + k0 + l * 8, &Bs[n * 512]);
    }
    __syncthreads();   // drain (compiler emits vmcnt(0) before s_barrier)
    #pragma unroll
    for (int ks = 0; ks < 4; ++ks) {
      const int ca = ((ks * 4 + quad) ^ l16) * 8;   // swizzled chunk offset
      short8 af0 = *(short8*)&As[(wm + l16) * 128 + ca];
      short8 af1 = *(short8*)&As[(wm + 16 + l16) * 128 + ca];
      short8 bg0 = *(short8*)&Bs[(wn + l16) * 128 + ca];
      short8 bg1 = *(short8*)&Bs[(wn + 16 + l16) * 128 + ca];
      acc[0][0] = __builtin_amdgcn_mfma_f32_16x16x32_bf16(af0, bg0, acc[0][0], 0, 0, 0);
      acc[0][1] = __builtin_amdgcn_mfma_f32_16x16x32_bf16(af0, bg1, acc[0][1], 0, 0, 0);
      acc[1][0] = __builtin_amdgcn_mfma_f32_16x16x32_bf16(af1, bg0, acc[1][0], 0, 0, 0);
      acc[1][1] = __builtin_amdgcn_mfma_f32_16x16x32_bf16(af1, bg1, acc[1][1], 0, 0, 0);
    }
  }

  #pragma unroll
  for (int mt = 0; mt < 2; ++mt)
    #pragma unroll
    for (int nt = 0; nt < 2; ++nt)
      #pragma unroll
      for (int r = 0; r < 4; ++r) {
        int row = m0 + wm + mt * 16 + quad * 4 + r;   // verified C/D layout
        int col = n0 + wn + nt * 16 + l16;
        float v = acc[mt][nt][r];
        if (mode == 1 || mode == 5) v += bias[col];
        if (mode == 2)
          outf[(size_t)row * ND + col] = v + bias[col] + resid[(size_t)row * ND + col];
        else if (mode == 5) {
          int bb = row >> 11, ss = row & 2047;
          outb[((size_t)bb * DV_ + col) * S_ + ss] = f_to_f16s(v);
        } else if (mode == 6) {
          short* dst = outb + ((col >> 10) ? (size_t)M_ * 1024 : 0) +
                       (size_t)row * 1024 + (col & 1023);
          *dst = f_to_f16s(v);
        } else if (mode == 4)
          outb[(size_t)row * ND + col] = f_to_f16s(v);
        else
          outb[(size_t)row * ND + col] = f_to_bf16s(v);
      }
}

// ---------------- fused collaborative attention v7 (counted-vmcnt) --------
// (Byte-identical to the R11 best: 468us measured.) R2/R8 structure with the
// per-step __syncthreads replaced by the T3/T4 counted-wait pattern: K
// triple-buffered (3x16KB), chunk t+2 issued at step t, consumed at t+2;
// end-of-step is raw s_barrier preceded by s_waitcnt vmcnt(8) (t<14;
// vmcnt(4) at t=14) which by in-order vmcnt retirement GUARANTEES chunk t+1
// is drained while leaving the newest 8 vmem ops in flight. R13's flattened
// variant (cross-tile pipeline, single-buffer Vt, direct-global cb)
// regressed 468->500 via +108MB L2 re-fetch; reverted.
__global__ __launch_bounds__(256, 2) void attn_kernel(
    const short* __restrict__ Qf, const short* __restrict__ Kf,
    const short* __restrict__ Vtf, const float* __restrict__ mixing,
    const float* __restrict__ CBs, short* __restrict__ ctxb) {
  __shared__ __align__(16) short KsF[3 * 128 * 64]; // 3 bufs, swizzled, 48 KB
  __shared__ __align__(16) short Vt[64][136];       // V^T tile [dv][j], f16
  __shared__ __align__(16) short mix_s[DK_];        // f16(mix*SC)
  __shared__ float cb_s[128];

  const int tid  = threadIdx.x;
  const int lane = tid & 63;
  const int l32  = lane & 31;
  const int l1   = lane >> 5;
  const int w    = tid >> 6;

  // XCD-locality remap: xcd class = blk&7; b per xcd-half, 4 heads per xcd
  const int F    = blockIdx.x;
  const int xcd  = F & 7, rest = F >> 3;
  const int b    = xcd >> 2;
  const int h    = (xcd & 3) * 4 + (rest & 3);
  const int i0   = (rest >> 2) * 128;

  const float SC = 0.125f * 1.44269504088896f;
  for (int c = tid; c < DK_; c += 256) {
    union { _Float16 h; short s; } cv;
    cv.h = (_Float16)(mixing[(size_t)h * DK_ + c] * SC);
    mix_s[c] = cv.s;
  }

  const int iq = i0 + w * 32 + l32;
  const short* qptr  = Qf + ((size_t)b * S_ + iq) * DK_;
  const short* kbase = Kf + (size_t)b * S_ * DK_;
  const short* vtb   = Vtf + ((size_t)b * DV_ + h * DH_) * S_;
  const float* cbp   = CBs + ((size_t)b * H_ + h) * S_;

  float16v accS[4], accO[2];
  #pragma unroll
  for (int g = 0; g < 2; ++g)
    #pragma unroll
    for (int r = 0; r < 16; ++r) accO[g][r] = 0.f;
  float m_run = -1e30f, l_run = 0.f;

  // K DMA geometry (64-col chunks): call n covers rows 8n..8n+7;
  // lane: row r = 8n + (lane>>3), phys 16B-chunk p = lane&7 holds
  // logical chunk l = p ^ (r&7)
  const int nrow = lane >> 3;
  const int dp8  = lane & 7;

  const int vrow = tid >> 2;             // Vt stage: 64 rows, 4 thr/row
  const int vseg = (tid & 3) * 32;

  for (int j0 = 0; j0 < S_; j0 += 128) {
    // ---- stage V^T + cb (reg round-trip, padded LDS) ----
    short8 vreg[4];
    #pragma unroll
    for (int c = 0; c < 4; ++c)
      vreg[c] = *(const short8*)(vtb + (size_t)vrow * S_ + j0 + vseg + c * 8);
    float cbv = 0.f;
    if (tid < 128) cbv = cbp[j0 + tid];
    __syncthreads();   // prev j-tile's Vt/cb/KsF consumers done
    #pragma unroll
    for (int c = 0; c < 4; ++c)
      *(short8*)&Vt[vrow][vseg + c * 8] = vreg[c];
    if (tid < 128) cb_s[tid] = cbv;

    // ---- pipeline prologue: issue chunks 0,1 (bufs 0,1), load q0 ----
    #pragma unroll
    for (int cc = 0; cc < 4; ++cc) {
      const int n = w * 4 + cc;
      const int r = 8 * n + nrow;
      const int lchunk = dp8 ^ (r & 7);
      gll16(kbase + (size_t)(j0 + r) * DK_ + lchunk * 8, &KsF[n * 512]);
    }
    #pragma unroll
    for (int cc = 0; cc < 4; ++cc) {
      const int n = w * 4 + cc;
      const int r = 8 * n + nrow;
      const int lchunk = dp8 ^ (r & 7);
      gll16(kbase + (size_t)(j0 + r) * DK_ + 64 + lchunk * 8,
            &KsF[8192 + n * 512]);
    }
    half8v qcur[4], qnext[4];
    #pragma unroll
    for (int ks = 0; ks < 4; ++ks) {
      qcur[ks] = *(const half8v*)(qptr + ks * 16 + l1 * 8);
      qnext[ks] = qcur[ks];
    }

    #pragma unroll
    for (int f = 0; f < 4; ++f)
      #pragma unroll
      for (int r = 0; r < 16; ++r) accS[f][r] = 0.f;

    // chunk0 drained (newest 8 = chunk1 + q0 may stay in flight),
    // Vt/cb ds_writes drained, then sync.
    __builtin_amdgcn_sched_barrier(0);
    asm volatile("s_waitcnt vmcnt(8) lgkmcnt(0)" ::: "memory");
    __builtin_amdgcn_s_barrier();
    __builtin_amdgcn_sched_barrier(0);

    int rd = 0;   // buffer holding chunk t
    for (int t = 0; t < 16; ++t) {
      // ---- issue chunk t+2 into buf (rd+2)%3, prefetch q(t+1) ----
      if (t < 14) {
        int wr = rd + 2; if (wr >= 3) wr -= 3;
        #pragma unroll
        for (int cc = 0; cc < 4; ++cc) {
          const int n = w * 4 + cc;
          const int r = 8 * n + nrow;
          const int lchunk = dp8 ^ (r & 7);
          gll16(kbase + (size_t)(j0 + r) * DK_ + (t + 2) * 64 + lchunk * 8,
                &KsF[wr * 8192 + n * 512]);
        }
      }
      if (t < 15) {
        #pragma unroll
        for (int ks = 0; ks < 4; ++ks)
          qnext[ks] = *(const half8v*)(qptr + (t + 1) * 64 + ks * 16 + l1 * 8);
      }
      // ---- compute chunk t from buf rd ----
      const short* kb = &KsF[rd * 8192];
      __builtin_amdgcn_s_setprio(1);
      #pragma unroll
      for (int ks = 0; ks < 4; ++ks) {
        half8v mf = *(half8v*)&mix_s[t * 64 + ks * 16 + l1 * 8];
        half8v qm = qcur[ks] * mf;                    // v_pk_mul_f16
        const int poff = (((2 * ks + l1) ^ (l32 & 7)) * 8) + l32 * 64;
        #pragma unroll
        for (int f = 0; f < 4; ++f) {
          half8v af = *(half8v*)&kb[f * 2048 + poff];
          accS[f] = __builtin_amdgcn_mfma_f32_32x32x16_f16(af, qm, accS[f], 0, 0, 0);
        }
      }
      __builtin_amdgcn_s_setprio(0);
      #pragma unroll
      for (int ks = 0; ks < 4; ++ks) qcur[ks] = qnext[ks];
      // ---- end-of-step: counted wait (chunk t+1 guaranteed drained by
      // in-order vmcnt retirement), raw barrier; no full drain ----
      if (t < 15) {
        __builtin_amdgcn_sched_barrier(0);
        if (t < 14) asm volatile("s_waitcnt vmcnt(8)" ::: "memory");
        else        asm volatile("s_waitcnt vmcnt(4)" ::: "memory");
        __builtin_amdgcn_s_barrier();
        __builtin_amdgcn_sched_barrier(0);
      }
      rd = (rd + 1 == 3) ? 0 : rd + 1;
    }

    // ---- online softmax: lane-local + 1 shfl ----
    float tmax = -1e30f;
    #pragma unroll
    for (int f = 0; f < 4; ++f)
      #pragma unroll
      for (int q = 0; q < 4; ++q) {
        float4 cbq = *(float4*)&cb_s[f * 32 + q * 8 + l1 * 4];
        #pragma unroll
        for (int c = 0; c < 4; ++c) {
          accS[f][4 * q + c] += ((const float*)&cbq)[c];
          tmax = fmaxf(tmax, accS[f][4 * q + c]);
        }
      }
    tmax = fmaxf(tmax, __shfl_xor(tmax, 32));
    const float mnew = fmaxf(m_run, tmax);
    const float alpha = exp2f(m_run - mnew);
    float tsum = 0.f;
    #pragma unroll
    for (int f = 0; f < 4; ++f)
      #pragma unroll
      for (int r = 0; r < 16; ++r) {
        float pv = exp2f(accS[f][r] - mnew);
        accS[f][r] = pv;
        tsum += pv;
      }
    tsum += __shfl_xor(tsum, 32);
    l_run = l_run * alpha + tsum;
    m_run = mnew;
    #pragma unroll
    for (int g = 0; g < 2; ++g)
      #pragma unroll
      for (int r = 0; r < 16; ++r) accO[g][r] *= alpha;

    // ---- PV: O^T[dv][i] += V^T[dv][j] @ P^T[j][i] ----
    #pragma unroll
    for (int cpv = 0; cpv < 8; ++cpv) {
      const int t = cpv & 1, fp = cpv >> 1;
      float xo[4], yo[4], lo[4], hi[4];
      #pragma unroll
      for (int c = 0; c < 4; ++c) {
        xo[c] = __shfl_xor(accS[fp][8 * t + c], 32);
        yo[c] = __shfl_xor(accS[fp][8 * t + 4 + c], 32);
      }
      #pragma unroll
      for (int c = 0; c < 4; ++c) {
        lo[c] = l1 ? yo[c] : accS[fp][8 * t + c];
        hi[c] = l1 ? accS[fp][8 * t + 4 + c] : xo[c];
      }
      union { half8v v; unsigned u[4]; } pb;
      pb.u[0] = pkrtz_u32(lo[0], lo[1]);
      pb.u[1] = pkrtz_u32(lo[2], lo[3]);
      pb.u[2] = pkrtz_u32(hi[0], hi[1]);
      pb.u[3] = pkrtz_u32(hi[2], hi[3]);
      #pragma unroll
      for (int g = 0; g < 2; ++g) {
        half8v vf = *(half8v*)&Vt[g * 32 + l32][cpv * 16 + l1 * 8];
        accO[g] = __builtin_amdgcn_mfma_f32_32x32x16_f16(vf, pb.v, accO[g], 0, 0, 0);
      }
    }
  }

  // ---- epilogue: normalize, store ctx (bf16) ----
  const float rl = 1.0f / l_run;
  short* cbase = ctxb + ((size_t)b * S_ + iq) * DV_ + h * DH_;
  #pragma unroll
  for (int g = 0; g < 2; ++g)
    #pragma unroll
    for (int q = 0; q < 4; ++q) {
      const int dv = g * 32 + 8 * q + 4 * l1;
      union { ushort4 u4; short s[4]; } ov;
      #pragma unroll
      for (int r = 0; r < 4; ++r)
        ov.s[r] = f_to_bf16s(accO[g][4 * q + r] * rl);
      *(ushort4*)(cbase + dv) = ov.u4;
    }
}

// ---------------- LayerNorm in-place on d_out ----------------
__global__ __launch_bounds__(256) void ln_kernel(float* __restrict__ out,
                                                 const float* __restrict__ gamma,
                                                 const float* __restrict__ beta) {
  __shared__ float red[8];
  const int row = blockIdx.x;
  const int tid = threadIdx.x;
  float* p = out + (size_t)row * DOUT_;
  float4 v = ((const float4*)p)[tid];
  float s = v.x + v.y + v.z + v.w;
  #pragma unroll
  for (int mk = 1; mk < 64; mk <<= 1) s += __shfl_xor(s, mk);
  if ((tid & 63) == 0) red[tid >> 6] = s;
  __syncthreads();
  const float mean = (red[0] + red[1] + red[2] + red[3]) * (1.0f / 1024.0f);
  const float d0 = v.x - mean, d1 = v.y - mean, d2 = v.z - mean, d3 = v.w - mean;
  float sq = d0 * d0 + d1 * d1 + d2 * d2 + d3 * d3;
  #pragma unroll
  for (int mk = 1; mk < 64; mk <<= 1) sq += __shfl_xor(sq, mk);
  if ((tid & 63) == 0) red[4 + (tid >> 6)] = sq;
  __syncthreads();
  const float var = (red[4] + red[5] + red[6] + red[7]) * (1.0f / 1024.0f);
  const float rstd = rsqrtf(var + 1e-5f);
  float4 g = ((const float4*)gamma)[tid];
  float4 bt = ((const float4*)beta)[tid];
  float4 o;
  o.x = d0 * rstd * g.x + bt.x;
  o.y = d1 * rstd * g.y + bt.y;
  o.z = d2 * rstd * g.z + bt.z;
  o.w = d3 * rstd * g.w + bt.w;
  ((float4*)p)[tid] = o;
}

extern "C" void kernel_launch(void* const* d_in, const int* in_sizes, int n_in,
                              void* d_out, int out_size, void* d_ws, size_t ws_size,
                              hipStream_t stream) {
  (void)in_sizes; (void)n_in; (void)out_size; (void)ws_size;
  const float* x      = (const float*)d_in[0];
  const float* Wq     = (const float*)d_in[1];
  const float* Wk     = (const float*)d_in[2];
  const float* Wcb    = (const float*)d_in[3];
  const float* Wv     = (const float*)d_in[4];
  const float* bv     = (const float*)d_in[5];
  const float* mixing = (const float*)d_in[6];
  const float* Wd     = (const float*)d_in[7];
  const float* bd     = (const float*)d_in[8];
  const float* gamma  = (const float*)d_in[9];
  const float* beta   = (const float*)d_in[10];
  float* out = (float*)d_out;

  short* p = (short*)d_ws;
  short* xb   = p; p += (size_t)M_ * DIN_;
  short* Qf   = p; p += (size_t)M_ * DK_;      // f16
  short* Kf   = p; p += (size_t)M_ * DK_;      // f16 (contiguous after Qf)
  short* Vtf  = p; p += (size_t)B_ * DV_ * S_; // f16, [b][dv][s]
  short* ctxb = p; p += (size_t)M_ * DV_;      // bf16
  short* Wqb  = p; p += (size_t)DK_ * DIN_;
  short* Wkb  = p; p += (size_t)DK_ * DIN_;    // contiguous after Wqb
  short* Wvb  = p; p += (size_t)DV_ * DIN_;
  short* Wdb  = p; p += (size_t)DOUT_ * DV_;
  float* CBs  = (float*)p;   // B*H*S floats
  (void)Kf; (void)Wkb;

  cast_kernel<<<dim3(M_ * DIN_ / 1024), 256, 0, stream>>>(x, xb, M_ * DIN_ / 4);
  cast_kernel<<<dim3(DK_ * DIN_ / 1024), 256, 0, stream>>>(Wq, Wqb, DK_ * DIN_ / 4);
  cast_kernel<<<dim3(DK_ * DIN_ / 1024), 256, 0, stream>>>(Wk, Wkb, DK_ * DIN_ / 4);
  cast_kernel<<<dim3(DV_ * DIN_ / 1024), 256, 0, stream>>>(Wv, Wvb, DV_ * DIN_ / 4);
  cast_kernel<<<dim3(DOUT_ * DV_ / 1024), 256, 0, stream>>>(Wd, Wdb, DOUT_ * DV_ / 4);
  cb_kernel<<<dim3(M_), 256, 0, stream>>>(x, Wcb, CBs);

  // fused Q||K projection: B = [Wqb;Wkb] (contiguous), out = [Qf;Kf] via mode 6
  dim3 gqk(2048 / 64, M_ / 64);
  gemm_nt<<<gqk, 256, 0, stream>>>(xb, Wqb, nullptr, nullptr, Qf, nullptr, 6);
  dim3 gg(DOUT_ / 64, M_ / 64);
  gemm_nt<<<gg, 256, 0, stream>>>(xb, Wvb, bv, nullptr, Vtf, nullptr, 5);

  attn_kernel<<<dim3(512), 256, 0, stream>>>(Qf, Kf, Vtf, mixing, CBs, ctxb);

  gemm_nt<<<gg, 256, 0, stream>>>(ctxb, Wdb, bd, x, nullptr, out, 2);
  ln_kernel<<<dim3(M_), 256, 0, stream>>>(out, gamma, beta);
}